// Round 8
// baseline (1428.321 us; speedup 1.0000x reference)
//
#include <hip/hip_runtime.h>
#include <hip/hip_bf16.h>
#include <stdint.h>

#define NN 100000
#define NE 1600000
#define NF 128
#define NTILE ((NN + 63) / 64)      // 1563 row tiles (gemm)
#define B_BKT 1563                  // aggregation buckets of 64 nodes
#define NB2 128                     // binning blocks
#define EPB (NE / NB2)              // 12500 edges per binning block
#define NCNT (B_BKT * NB2)          // 200,064 segment counters
#define SC2A ((NCNT + 255) / 256)   // 782 scan blocks

typedef __attribute__((ext_vector_type(8))) __bf16 bf16x8;
typedef __attribute__((ext_vector_type(4))) float floatx4;
typedef __attribute__((ext_vector_type(4))) unsigned short ushortx4;
typedef __attribute__((ext_vector_type(8))) unsigned short ushortx8;

static __device__ __forceinline__ unsigned short f2bf(float x) {
    union { float f; unsigned u; } v; v.f = x;
    unsigned r = v.u + 0x7fffu + ((v.u >> 16) & 1u);   // RNE
    return (unsigned short)(r >> 16);
}
static __device__ __forceinline__ float bflo(unsigned w) {
    union { unsigned u; float f; } v; v.u = w << 16; return v.f;
}
static __device__ __forceinline__ float bfhi(unsigned w) {
    union { unsigned u; float f; } v; v.u = w & 0xffff0000u; return v.f;
}

// fp32 -> bf16
__global__ void k_convert(const float* __restrict__ s, unsigned short* __restrict__ d, int n4) {
    int i = blockIdx.x * blockDim.x + threadIdx.x;
    if (i < n4) {
        floatx4 f = __builtin_nontemporal_load((const floatx4*)s + i);
        ushortx4 o;
        o.x = f2bf(f.x); o.y = f2bf(f.y); o.z = f2bf(f.z); o.w = f2bf(f.w);
        ((ushortx4*)d)[i] = o;
    }
}

// Build W2t: [n][k] bf16, k in 0..255 = [Wv ; Wu], 16B k-chunks XOR-swizzled
__global__ void k_prep(const float* __restrict__ wv, const float* __restrict__ wu,
                       unsigned short* __restrict__ w2t) {
    int id = blockIdx.x * 256 + threadIdx.x;   // 0..4095
    if (id >= 128 * 32) return;
    int n = id >> 5, kg = id & 31;
    const float* srcm = (kg < 16) ? wv : wu;
    int k0 = (kg & 15) * 8;
    ushortx8 o;
#pragma unroll
    for (int j = 0; j < 8; ++j)
        o[j] = f2bf(srcm[(k0 + j) * 128 + n]);
    int dchunk = n * 32 + (kg ^ (n & 7));
    *(ushortx8*)(w2t + dchunk * 8) = o;
}

// pass 1: per-block histogram over 1563 fine buckets (LDS atomics only)
__global__ void k_count(const int* __restrict__ dst, int* __restrict__ counts) {
    __shared__ int h[B_BKT];
    int tid = threadIdx.x;
    for (int i = tid; i < B_BKT; i += 256) h[i] = 0;
    __syncthreads();
    int base = blockIdx.x * EPB, end = base + EPB;
    for (int i = base + tid; i < end; i += 256) {
        int d = __builtin_nontemporal_load(&dst[i]);
        atomicAdd(&h[d >> 6], 1);
    }
    __syncthreads();
    for (int i = tid; i < B_BKT; i += 256)
        counts[i * NB2 + blockIdx.x] = h[i];
}

// hierarchical exclusive scan of the 200,064 counts (bucket-major)
__global__ void k_scan2_a(int* __restrict__ counts, int* __restrict__ bsums) {
    __shared__ int sh[256];
    int i = blockIdx.x * 256 + threadIdx.x;
    int v = (i < NCNT) ? counts[i] : 0;
    sh[threadIdx.x] = v;
    __syncthreads();
    for (int off = 1; off < 256; off <<= 1) {
        int u = (threadIdx.x >= off) ? sh[threadIdx.x - off] : 0;
        __syncthreads();
        sh[threadIdx.x] += u;
        __syncthreads();
    }
    if (i < NCNT) counts[i] = sh[threadIdx.x] - v;
    if (threadIdx.x == 255) bsums[blockIdx.x] = sh[255];
}
__global__ void k_scan2_b(int* __restrict__ bsums) {
    __shared__ int sh[1024];
    int t = threadIdx.x;
    int v = (t < SC2A) ? bsums[t] : 0;
    sh[t] = v;
    __syncthreads();
    for (int off = 1; off < 1024; off <<= 1) {
        int u = (t >= off) ? sh[t - off] : 0;
        __syncthreads();
        sh[t] += u;
        __syncthreads();
    }
    if (t < SC2A) bsums[t] = sh[t] - v;
}
__global__ void k_scan2_c(int* __restrict__ counts, const int* __restrict__ bsums) {
    int i = blockIdx.x * 256 + threadIdx.x;
    if (i < NCNT) counts[i] += bsums[blockIdx.x];
}

// pass 2: deterministic scatter into bucket-sorted stream; LDS cursors only
__global__ void k_binscatter(const int* __restrict__ src, const int* __restrict__ dst,
                             const int* __restrict__ counts, unsigned* __restrict__ streams) {
    __shared__ int cur[B_BKT];
    int tid = threadIdx.x;
    for (int i = tid; i < B_BKT; i += 256)
        cur[i] = counts[i * NB2 + blockIdx.x];
    __syncthreads();
    int base = blockIdx.x * EPB, end = base + EPB;
    for (int i = base + tid; i < end; i += 256) {
        int d = __builtin_nontemporal_load(&dst[i]);
        int s = __builtin_nontemporal_load(&src[i]);
        int b = d >> 6;
        unsigned packed = ((unsigned)(d & 63) << 17) | (unsigned)s;
        int pos = atomicAdd(&cur[b], 1);
        streams[pos] = packed;
    }
}

// bucket aggregation: one block per 64-node bucket; fp32 accumulate in LDS
// (two de-interleaved planes -> 2-way bank aliasing = free), deg in LDS,
// scale by 1/max(deg,1), coalesced bf16 writeout. No CSR, no global atomics.
__global__ void k_bagg(const unsigned short* __restrict__ featb,
                       const int* __restrict__ counts,
                       const unsigned* __restrict__ streams,
                       unsigned short* __restrict__ aggb) {
    __shared__ float alo[64 * 64];
    __shared__ float ahi[64 * 64];
    __shared__ int dcnt[64];
    int tid = threadIdx.x;
    int lane = tid & 63, wave = tid >> 6;
    int bkt = blockIdx.x;
    for (int i = tid; i < 4096; i += 256) { alo[i] = 0.f; ahi[i] = 0.f; }
    if (tid < 64) dcnt[tid] = 0;
    __syncthreads();

    int s = counts[bkt * NB2];
    int e = (bkt == B_BKT - 1) ? NE : counts[(bkt + 1) * NB2];

    for (int base = s + wave * 64; base < e; base += 256) {
        unsigned pk = 0;
        if (base + lane < e) {
            pk = streams[base + lane];
            atomicAdd(&dcnt[pk >> 17], 1);
        }
        int m = e - base; if (m > 64) m = 64;
        int j = 0;
        for (; j + 8 <= m; j += 8) {                    // 8 gathers in flight
            unsigned p0 = __shfl(pk, j + 0, 64), p1 = __shfl(pk, j + 1, 64);
            unsigned p2 = __shfl(pk, j + 2, 64), p3 = __shfl(pk, j + 3, 64);
            unsigned p4 = __shfl(pk, j + 4, 64), p5 = __shfl(pk, j + 5, 64);
            unsigned p6 = __shfl(pk, j + 6, 64), p7 = __shfl(pk, j + 7, 64);
            unsigned w0 = *(const unsigned*)(featb + (size_t)(p0 & 0x1FFFFu) * NF + lane * 2);
            unsigned w1 = *(const unsigned*)(featb + (size_t)(p1 & 0x1FFFFu) * NF + lane * 2);
            unsigned w2 = *(const unsigned*)(featb + (size_t)(p2 & 0x1FFFFu) * NF + lane * 2);
            unsigned w3 = *(const unsigned*)(featb + (size_t)(p3 & 0x1FFFFu) * NF + lane * 2);
            unsigned w4 = *(const unsigned*)(featb + (size_t)(p4 & 0x1FFFFu) * NF + lane * 2);
            unsigned w5 = *(const unsigned*)(featb + (size_t)(p5 & 0x1FFFFu) * NF + lane * 2);
            unsigned w6 = *(const unsigned*)(featb + (size_t)(p6 & 0x1FFFFu) * NF + lane * 2);
            unsigned w7 = *(const unsigned*)(featb + (size_t)(p7 & 0x1FFFFu) * NF + lane * 2);
            atomicAdd(&alo[(p0 >> 17) * 64 + lane], bflo(w0));
            atomicAdd(&ahi[(p0 >> 17) * 64 + lane], bfhi(w0));
            atomicAdd(&alo[(p1 >> 17) * 64 + lane], bflo(w1));
            atomicAdd(&ahi[(p1 >> 17) * 64 + lane], bfhi(w1));
            atomicAdd(&alo[(p2 >> 17) * 64 + lane], bflo(w2));
            atomicAdd(&ahi[(p2 >> 17) * 64 + lane], bfhi(w2));
            atomicAdd(&alo[(p3 >> 17) * 64 + lane], bflo(w3));
            atomicAdd(&ahi[(p3 >> 17) * 64 + lane], bfhi(w3));
            atomicAdd(&alo[(p4 >> 17) * 64 + lane], bflo(w4));
            atomicAdd(&ahi[(p4 >> 17) * 64 + lane], bfhi(w4));
            atomicAdd(&alo[(p5 >> 17) * 64 + lane], bflo(w5));
            atomicAdd(&ahi[(p5 >> 17) * 64 + lane], bfhi(w5));
            atomicAdd(&alo[(p6 >> 17) * 64 + lane], bflo(w6));
            atomicAdd(&ahi[(p6 >> 17) * 64 + lane], bfhi(w6));
            atomicAdd(&alo[(p7 >> 17) * 64 + lane], bflo(w7));
            atomicAdd(&ahi[(p7 >> 17) * 64 + lane], bfhi(w7));
        }
        for (; j < m; ++j) {
            unsigned p = __shfl(pk, j, 64);
            unsigned w = *(const unsigned*)(featb + (size_t)(p & 0x1FFFFu) * NF + lane * 2);
            atomicAdd(&alo[(p >> 17) * 64 + lane], bflo(w));
            atomicAdd(&ahi[(p >> 17) * 64 + lane], bfhi(w));
        }
    }
    __syncthreads();

    for (int n = wave; n < 64; n += 4) {
        int g = bkt * 64 + n;
        if (g >= NN) break;
        int dg = dcnt[n]; if (dg < 1) dg = 1;
        float sc = 1.0f / (float)dg;
        unsigned outw = ((unsigned)f2bf(ahi[n * 64 + lane] * sc) << 16)
                      | (unsigned)f2bf(alo[n * 64 + lane] * sc);
        *(unsigned*)(aggb + (size_t)g * NF + lane * 2) = outw;
    }
}

// single fused GEMM: out = relu([feat | agg_n] @ W2 + bias), K=256
__global__ __launch_bounds__(256, 2) void k_gemm(
    const unsigned short* __restrict__ featb,
    const unsigned short* __restrict__ aggb,
    const unsigned short* __restrict__ w2t,
    const float* __restrict__ bias,
    float* __restrict__ out) {
    __shared__ unsigned short lds[128 * 256];   // 64 KiB
    for (int i = threadIdx.x; i < 4096; i += 256) {
        ushortx8 w = *(const ushortx8*)(w2t + i * 8);
        *(ushortx8*)(&lds[i * 8]) = w;
    }
    __syncthreads();

    int lane = threadIdx.x & 63;
    int wave = threadIdx.x >> 6;
    int quad = lane >> 4, l15 = lane & 15;

    float bsv[8];
#pragma unroll
    for (int ct = 0; ct < 8; ++ct) bsv[ct] = bias[ct * 16 + l15];

    for (int t = blockIdx.x; t < NTILE; t += gridDim.x) {
        int rb = t * 64 + wave * 16;
        int arow = rb + l15; if (arow > NN - 1) arow = NN - 1;
        const unsigned short* fr = featb + (size_t)arow * NF;
        const unsigned short* ar = aggb + (size_t)arow * NF;
        bf16x8 a[8];
#pragma unroll
        for (int ks = 0; ks < 4; ++ks) {
            a[ks]     = *(const bf16x8*)(fr + ks * 32 + quad * 8);
            a[4 + ks] = *(const bf16x8*)(ar + ks * 32 + quad * 8);
        }
        floatx4 acc[8];
#pragma unroll
        for (int ct = 0; ct < 8; ++ct) acc[ct] = (floatx4){0.f, 0.f, 0.f, 0.f};
#pragma unroll
        for (int ct = 0; ct < 8; ++ct) {
            int n = ct * 16 + l15;
            int rowoff = n << 8;
            int sw = n & 7;
#pragma unroll
            for (int ks = 0; ks < 8; ++ks) {
                int kg = ks * 4 + quad;
                bf16x8 b = *(const bf16x8*)(&lds[rowoff + ((kg ^ sw) << 3)]);
                acc[ct] = __builtin_amdgcn_mfma_f32_16x16x32_bf16(a[ks], b, acc[ct], 0, 0, 0);
            }
        }
#pragma unroll
        for (int ct = 0; ct < 8; ++ct) {
            int col = ct * 16 + l15;
#pragma unroll
            for (int r = 0; r < 4; ++r) {
                int row = rb + quad * 4 + r;
                if (row < NN) {
                    float v = acc[ct][r] + bsv[ct];
                    out[(size_t)row * NF + col] = v > 0.f ? v : 0.f;
                }
            }
        }
    }
}

extern "C" void kernel_launch(void* const* d_in, const int* in_sizes, int n_in,
                              void* d_out, int out_size, void* d_ws, size_t ws_size,
                              hipStream_t stream) {
    const float* feat = (const float*)d_in[0];
    const float* wu   = (const float*)d_in[1];
    const float* wv   = (const float*)d_in[2];
    const float* bias = (const float*)d_in[3];
    const int* src    = (const int*)d_in[4];
    const int* dst    = (const int*)d_in[5];
    float* out        = (float*)d_out;

    char* ws = (char*)d_ws;
    int* counts           = (int*)(ws + 0);                    //   800,256 B
    int* bsums            = (int*)(ws + 800256);               //     4,096 B
    unsigned* streams     = (unsigned*)(ws + 804352);          // 6,400,000 B
    unsigned short* featb = (unsigned short*)(ws + 7204352);   // 25,600,000 B
    unsigned short* aggb  = (unsigned short*)(ws + 32804352);  // 25,600,000 B
    unsigned short* w2t   = (unsigned short*)(ws + 58404352);  //    65,536 B

    k_convert<<<(NN * NF / 4 + 255) / 256, 256, 0, stream>>>(feat, featb, NN * NF / 4);
    k_prep<<<16, 256, 0, stream>>>(wv, wu, w2t);

    k_count<<<NB2, 256, 0, stream>>>(dst, counts);
    k_scan2_a<<<SC2A, 256, 0, stream>>>(counts, bsums);
    k_scan2_b<<<1, 1024, 0, stream>>>(bsums);
    k_scan2_c<<<SC2A, 256, 0, stream>>>(counts, bsums);
    k_binscatter<<<NB2, 256, 0, stream>>>(src, dst, counts, streams);
    k_bagg<<<B_BKT, 256, 0, stream>>>(featb, counts, streams, aggb);
    k_gemm<<<768, 256, 0, stream>>>(featb, aggb, w2t, bias, out);
}

// Round 9
// 313.797 us; speedup vs baseline: 4.5517x; 4.5517x over previous
//
#include <hip/hip_runtime.h>
#include <hip/hip_bf16.h>
#include <stdint.h>

#define NN 100000
#define NE 1600000
#define NF 128
#define NTILE ((NN + 63) / 64)      // 1563 row tiles (gemm)
#define B_BKT 1563                  // 64-node buckets
#define NB2 128                     // binning blocks
#define EPB (NE / NB2)              // 12500 edges per binning block
#define NCNT (B_BKT * NB2)          // 200,064 segment counters
#define SC2A ((NCNT + 255) / 256)   // 782 scan blocks

typedef __attribute__((ext_vector_type(8))) __bf16 bf16x8;
typedef __attribute__((ext_vector_type(4))) float floatx4;
typedef __attribute__((ext_vector_type(4))) unsigned short ushortx4;
typedef __attribute__((ext_vector_type(8))) unsigned short ushortx8;

static __device__ __forceinline__ unsigned short f2bf(float x) {
    union { float f; unsigned u; } v; v.f = x;
    unsigned r = v.u + 0x7fffu + ((v.u >> 16) & 1u);   // RNE
    return (unsigned short)(r >> 16);
}
static __device__ __forceinline__ float bflo(unsigned w) {
    union { unsigned u; float f; } v; v.u = w << 16; return v.f;
}
static __device__ __forceinline__ float bfhi(unsigned w) {
    union { unsigned u; float f; } v; v.u = w & 0xffff0000u; return v.f;
}

// fp32 -> bf16
__global__ void k_convert(const float* __restrict__ s, unsigned short* __restrict__ d, int n4) {
    int i = blockIdx.x * blockDim.x + threadIdx.x;
    if (i < n4) {
        floatx4 f = __builtin_nontemporal_load((const floatx4*)s + i);
        ushortx4 o;
        o.x = f2bf(f.x); o.y = f2bf(f.y); o.z = f2bf(f.z); o.w = f2bf(f.w);
        ((ushortx4*)d)[i] = o;
    }
}

// Build W2t: [n][k] bf16, k in 0..255 = [Wv ; Wu], 16B k-chunks XOR-swizzled
__global__ void k_prep(const float* __restrict__ wv, const float* __restrict__ wu,
                       unsigned short* __restrict__ w2t) {
    int id = blockIdx.x * 256 + threadIdx.x;   // 0..4095
    if (id >= 128 * 32) return;
    int n = id >> 5, kg = id & 31;
    const float* srcm = (kg < 16) ? wv : wu;
    int k0 = (kg & 15) * 8;
    ushortx8 o;
#pragma unroll
    for (int j = 0; j < 8; ++j)
        o[j] = f2bf(srcm[(k0 + j) * 128 + n]);
    int dchunk = n * 32 + (kg ^ (n & 7));
    *(ushortx8*)(w2t + dchunk * 8) = o;
}

// pass 1: per-block histogram over 1563 fine buckets (LDS atomics only)
__global__ void k_count(const int* __restrict__ dst, int* __restrict__ counts) {
    __shared__ int h[B_BKT];
    int tid = threadIdx.x;
    for (int i = tid; i < B_BKT; i += 256) h[i] = 0;
    __syncthreads();
    int base = blockIdx.x * EPB, end = base + EPB;
    for (int i = base + tid; i < end; i += 256) {
        int d = __builtin_nontemporal_load(&dst[i]);
        atomicAdd(&h[d >> 6], 1);
    }
    __syncthreads();
    for (int i = tid; i < B_BKT; i += 256)
        counts[i * NB2 + blockIdx.x] = h[i];
}

// hierarchical exclusive scan of the 200,064 counts (bucket-major)
__global__ void k_scan2_a(int* __restrict__ counts, int* __restrict__ bsums) {
    __shared__ int sh[256];
    int i = blockIdx.x * 256 + threadIdx.x;
    int v = (i < NCNT) ? counts[i] : 0;
    sh[threadIdx.x] = v;
    __syncthreads();
    for (int off = 1; off < 256; off <<= 1) {
        int u = (threadIdx.x >= off) ? sh[threadIdx.x - off] : 0;
        __syncthreads();
        sh[threadIdx.x] += u;
        __syncthreads();
    }
    if (i < NCNT) counts[i] = sh[threadIdx.x] - v;
    if (threadIdx.x == 255) bsums[blockIdx.x] = sh[255];
}
__global__ void k_scan2_b(int* __restrict__ bsums) {
    __shared__ int sh[1024];
    int t = threadIdx.x;
    int v = (t < SC2A) ? bsums[t] : 0;
    sh[t] = v;
    __syncthreads();
    for (int off = 1; off < 1024; off <<= 1) {
        int u = (t >= off) ? sh[t - off] : 0;
        __syncthreads();
        sh[t] += u;
        __syncthreads();
    }
    if (t < SC2A) bsums[t] = sh[t] - v;
}
__global__ void k_scan2_c(int* __restrict__ counts, const int* __restrict__ bsums) {
    int i = blockIdx.x * 256 + threadIdx.x;
    if (i < NCNT) counts[i] += bsums[blockIdx.x];
}

// pass 2: deterministic scatter into bucket-sorted stream; LDS cursors only
__global__ void k_binscatter(const int* __restrict__ src, const int* __restrict__ dst,
                             const int* __restrict__ counts, unsigned* __restrict__ streams) {
    __shared__ int cur[B_BKT];
    int tid = threadIdx.x;
    for (int i = tid; i < B_BKT; i += 256)
        cur[i] = counts[i * NB2 + blockIdx.x];
    __syncthreads();
    int base = blockIdx.x * EPB, end = base + EPB;
    for (int i = base + tid; i < end; i += 256) {
        int d = __builtin_nontemporal_load(&dst[i]);
        int s = __builtin_nontemporal_load(&src[i]);
        int b = d >> 6;
        unsigned packed = ((unsigned)(d & 63) << 17) | (unsigned)s;
        int pos = atomicAdd(&cur[b], 1);
        streams[pos] = packed;
    }
}

// finalize CSR per bucket: histogram 64 nodes, tiny serial scan, write offs,
// scatter src into the block's OWN contiguous [s,e) csr range (L2-local,
// full-line writeback once — no cross-block write amplification)
__global__ void k_csr(const unsigned* __restrict__ streams,
                      const int* __restrict__ counts,
                      int* __restrict__ offs, int* __restrict__ csr) {
    __shared__ int hist[64];
    __shared__ int nodeoff[65];
    int tid = threadIdx.x;
    int bkt = blockIdx.x;
    int s = counts[bkt * NB2];
    int e = (bkt == B_BKT - 1) ? NE : counts[(bkt + 1) * NB2];
    if (tid < 64) hist[tid] = 0;
    __syncthreads();
    for (int i = s + tid; i < e; i += 256)
        atomicAdd(&hist[streams[i] >> 17], 1);
    __syncthreads();
    if (tid == 0) {
        int run = 0;
#pragma unroll
        for (int n = 0; n < 64; ++n) { nodeoff[n] = run; run += hist[n]; }
        nodeoff[64] = run;
    }
    __syncthreads();
    if (tid < 64) {
        int node = bkt * 64 + tid;
        if (node < NN) offs[node] = s + nodeoff[tid];
        hist[tid] = nodeoff[tid];          // reuse as relative cursor
    }
    if (bkt == B_BKT - 1 && tid == 0) offs[NN] = NE;
    __syncthreads();
    for (int i = s + tid; i < e; i += 256) {
        unsigned v = streams[i];
        int p = atomicAdd(&hist[v >> 17], 1);
        csr[s + p] = (int)(v & 0x1FFFFu);
    }
}

// one wave per node: fp32 accumulate of bf16 feat rows, scale by 1/max(deg,1)
__global__ void k_aggregate(const unsigned short* __restrict__ featb,
                            const int* __restrict__ offs,
                            const int* __restrict__ csr,
                            unsigned short* __restrict__ aggb) {
    int lane = threadIdx.x & 63;
    int node = blockIdx.x * 4 + (threadIdx.x >> 6);
    if (node >= NN) return;
    int s0 = offs[node], s1 = offs[node + 1];
    float a0 = 0.f, a1 = 0.f;
    for (int base = s0; base < s1; base += 64) {
        int e = (base + lane < s1) ? csr[base + lane] : 0;
        int m = s1 - base; if (m > 64) m = 64;
        int j = 0;
        for (; j + 8 <= m; j += 8) {                    // 8 loads in flight
            unsigned w0 = *(const unsigned*)(featb + (size_t)__shfl(e, j + 0, 64) * NF + lane * 2);
            unsigned w1 = *(const unsigned*)(featb + (size_t)__shfl(e, j + 1, 64) * NF + lane * 2);
            unsigned w2 = *(const unsigned*)(featb + (size_t)__shfl(e, j + 2, 64) * NF + lane * 2);
            unsigned w3 = *(const unsigned*)(featb + (size_t)__shfl(e, j + 3, 64) * NF + lane * 2);
            unsigned w4 = *(const unsigned*)(featb + (size_t)__shfl(e, j + 4, 64) * NF + lane * 2);
            unsigned w5 = *(const unsigned*)(featb + (size_t)__shfl(e, j + 5, 64) * NF + lane * 2);
            unsigned w6 = *(const unsigned*)(featb + (size_t)__shfl(e, j + 6, 64) * NF + lane * 2);
            unsigned w7 = *(const unsigned*)(featb + (size_t)__shfl(e, j + 7, 64) * NF + lane * 2);
            a0 += bflo(w0) + bflo(w1) + bflo(w2) + bflo(w3)
                + bflo(w4) + bflo(w5) + bflo(w6) + bflo(w7);
            a1 += bfhi(w0) + bfhi(w1) + bfhi(w2) + bfhi(w3)
                + bfhi(w4) + bfhi(w5) + bfhi(w6) + bfhi(w7);
        }
        for (; j < m; ++j) {
            int nn = __shfl(e, j, 64);
            unsigned w = *(const unsigned*)(featb + (size_t)nn * NF + lane * 2);
            a0 += bflo(w); a1 += bfhi(w);
        }
    }
    int dg = s1 - s0; if (dg < 1) dg = 1;
    float scale = 1.0f / (float)dg;
    unsigned outw = ((unsigned)f2bf(a1 * scale) << 16) | (unsigned)f2bf(a0 * scale);
    *(unsigned*)(aggb + (size_t)node * NF + lane * 2) = outw;
}

// single fused GEMM: out = relu([feat | agg_n] @ W2 + bias), K=256
__global__ __launch_bounds__(256, 2) void k_gemm(
    const unsigned short* __restrict__ featb,
    const unsigned short* __restrict__ aggb,
    const unsigned short* __restrict__ w2t,
    const float* __restrict__ bias,
    float* __restrict__ out) {
    __shared__ unsigned short lds[128 * 256];   // 64 KiB
    for (int i = threadIdx.x; i < 4096; i += 256) {
        ushortx8 w = *(const ushortx8*)(w2t + i * 8);
        *(ushortx8*)(&lds[i * 8]) = w;
    }
    __syncthreads();

    int lane = threadIdx.x & 63;
    int wave = threadIdx.x >> 6;
    int quad = lane >> 4, l15 = lane & 15;

    float bsv[8];
#pragma unroll
    for (int ct = 0; ct < 8; ++ct) bsv[ct] = bias[ct * 16 + l15];

    for (int t = blockIdx.x; t < NTILE; t += gridDim.x) {
        int rb = t * 64 + wave * 16;
        int arow = rb + l15; if (arow > NN - 1) arow = NN - 1;
        const unsigned short* fr = featb + (size_t)arow * NF;
        const unsigned short* ar = aggb + (size_t)arow * NF;
        bf16x8 a[8];
#pragma unroll
        for (int ks = 0; ks < 4; ++ks) {
            a[ks]     = *(const bf16x8*)(fr + ks * 32 + quad * 8);
            a[4 + ks] = *(const bf16x8*)(ar + ks * 32 + quad * 8);
        }
        floatx4 acc[8];
#pragma unroll
        for (int ct = 0; ct < 8; ++ct) acc[ct] = (floatx4){0.f, 0.f, 0.f, 0.f};
#pragma unroll
        for (int ct = 0; ct < 8; ++ct) {
            int n = ct * 16 + l15;
            int rowoff = n << 8;
            int sw = n & 7;
#pragma unroll
            for (int ks = 0; ks < 8; ++ks) {
                int kg = ks * 4 + quad;
                bf16x8 b = *(const bf16x8*)(&lds[rowoff + ((kg ^ sw) << 3)]);
                acc[ct] = __builtin_amdgcn_mfma_f32_16x16x32_bf16(a[ks], b, acc[ct], 0, 0, 0);
            }
        }
#pragma unroll
        for (int ct = 0; ct < 8; ++ct) {
            int col = ct * 16 + l15;
#pragma unroll
            for (int r = 0; r < 4; ++r) {
                int row = rb + quad * 4 + r;
                if (row < NN) {
                    float v = acc[ct][r] + bsv[ct];
                    out[(size_t)row * NF + col] = v > 0.f ? v : 0.f;
                }
            }
        }
    }
}

extern "C" void kernel_launch(void* const* d_in, const int* in_sizes, int n_in,
                              void* d_out, int out_size, void* d_ws, size_t ws_size,
                              hipStream_t stream) {
    const float* feat = (const float*)d_in[0];
    const float* wu   = (const float*)d_in[1];
    const float* wv   = (const float*)d_in[2];
    const float* bias = (const float*)d_in[3];
    const int* src    = (const int*)d_in[4];
    const int* dst    = (const int*)d_in[5];
    float* out        = (float*)d_out;

    char* ws = (char*)d_ws;
    int* counts           = (int*)(ws + 0);                    //   800,256 B
    int* bsums            = (int*)(ws + 800256);               //     4,096 B
    int* offs             = (int*)(ws + 804352);               //   400,004 B
    int* csr              = (int*)(ws + 1204480);              // 6,400,000 B
    unsigned short* featb = (unsigned short*)(ws + 7604480);   // 25,600,000 B
    unsigned short* aggb  = (unsigned short*)(ws + 33204480);  // 25,600,000 B
    unsigned short* w2t   = (unsigned short*)(ws + 58804480);  //    65,536 B
    // streams aliases aggb: dead (after k_csr) before k_aggregate writes aggb
    unsigned* streams     = (unsigned*)aggb;                   // 6.4 MB

    k_convert<<<(NN * NF / 4 + 255) / 256, 256, 0, stream>>>(feat, featb, NN * NF / 4);
    k_prep<<<16, 256, 0, stream>>>(wv, wu, w2t);

    k_count<<<NB2, 256, 0, stream>>>(dst, counts);
    k_scan2_a<<<SC2A, 256, 0, stream>>>(counts, bsums);
    k_scan2_b<<<1, 1024, 0, stream>>>(bsums);
    k_scan2_c<<<SC2A, 256, 0, stream>>>(counts, bsums);
    k_binscatter<<<NB2, 256, 0, stream>>>(src, dst, counts, streams);
    k_csr<<<B_BKT, 256, 0, stream>>>(streams, counts, offs, csr);
    k_aggregate<<<(NN + 3) / 4, 256, 0, stream>>>(featb, offs, csr, aggb);
    k_gemm<<<768, 256, 0, stream>>>(featb, aggb, w2t, bias, out);
}